// Round 4
// baseline (283.369 us; speedup 1.0000x reference)
//
#include <hip/hip_runtime.h>
#include <math.h>

#define N_NODES 4096
#define N_EDGES 8192
#define N_GRAPHS 256
#define D_NODE 64
#define D_EDGE 32
#define HH 256

#define K1 2176   // 33*64 (edge-MLP + nn_b rows) + 64 (x augment for root1)
#define K2 8704   // 33*256 + 256 (h augment for root2)
#define NC1 34
#define NC2 136
#define NSL1 8    // split-K slices conv1
#define NSL3 32   // split-K slices pooled conv2 mini-GEMM
#define CHUNK 64  // sg_k edge chunk

typedef _Float16 half8v __attribute__((ext_vector_type(8)));
typedef _Float16 half4v __attribute__((ext_vector_type(4)));
typedef float floatx4 __attribute__((ext_vector_type(4)));

// ---------------- workspace layout (float offsets) ----------------
static const size_t OFF_S    = 0;              // S1 fp16 [4096x2176]; later SG fp16 [256x8704] (time-disjoint)
static const size_t OFF_BT1  = 17825792;       // BT1 fp16: 256 x 2176 halves
static const size_t OFF_BT2  = 18104320;       // BT2 fp16: 256 x 8704 halves
static const size_t OFF_CP   = 19218432;       // Cpart fp16 (conv1, 8 slices); later CpS f32 [32][256][256]
static const size_t OFF_H    = 25509888;       // h fp16: 524,288 floats
static const size_t OFF_INT  = 26034176;       // starts[4097] + pad + elist[8192]

// ---------------- prep: CSR build (block 0) + weight pack (other blocks) ----------------
__device__ void csr_body(const int* __restrict__ dst,
                         int* __restrict__ starts,
                         int* __restrict__ elist) {
    __shared__ int cnt[4096];
    __shared__ int ps[256];
    int t = threadIdx.x;
#pragma unroll
    for (int i = 0; i < 16; ++i) cnt[t * 16 + i] = 0;
    __syncthreads();
#pragma unroll
    for (int i = 0; i < 32; ++i) atomicAdd(&cnt[dst[i * 256 + t]], 1);
    __syncthreads();
    int v[16]; int s = 0;
#pragma unroll
    for (int i = 0; i < 16; ++i) { v[i] = cnt[t * 16 + i]; s += v[i]; }
    ps[t] = s;
    __syncthreads();
    for (int off = 1; off < 256; off <<= 1) {
        int tv = (t >= off) ? ps[t - off] : 0;
        __syncthreads();
        ps[t] += tv;
        __syncthreads();
    }
    int excl = ps[t] - s;
#pragma unroll
    for (int i = 0; i < 16; ++i) {
        starts[t * 16 + i] = excl;
        cnt[t * 16 + i] = excl;       // becomes cursor
        excl += v[i];
    }
    if (t == 255) starts[4096] = excl;
    __syncthreads();
#pragma unroll
    for (int i = 0; i < 32; ++i) {
        int e = i * 256 + t;
        int d = dst[e];
        int p = atomicAdd(&cnt[d], 1);
        elist[p] = e;
    }
}

__device__ void packT_body(const float* __restrict__ w,
                           const float* __restrict__ b,
                           const float* __restrict__ rw,
                           _Float16* __restrict__ BT,
                           int kk0, int o0, int K,
                           int wlim, int blim, int wshift, int wmask, int wrow) {
    __shared__ float T[64][65];
    int t = threadIdx.x;
    int ol = t & 63, kb = t >> 6;
#pragma unroll
    for (int p = 0; p < 16; ++p) {
        int kl = p * 4 + kb;
        int kk = kk0 + kl, o = o0 + ol;
        float v;
        if (kk < wlim)      v = w[(kk >> wshift) * wrow + (kk & wmask) * 256 + o];
        else if (kk < blim) v = b[(kk - wlim) * 256 + o];
        else                v = rw[(kk - blim) * 256 + o];
        T[kl][ol] = v;
    }
    __syncthreads();
    int kl2 = t & 63, ob = t >> 6;
#pragma unroll
    for (int p = 0; p < 16; ++p) {
        int ol2 = p * 4 + ob;
        BT[(size_t)(o0 + ol2) * K + kk0 + kl2] = (_Float16)T[kl2][ol2];
    }
}

__global__ __launch_bounds__(256) void prep_k(const int* __restrict__ dst,
                                              int* __restrict__ starts,
                                              int* __restrict__ elist,
                                              const float* __restrict__ w1,
                                              const float* __restrict__ b1,
                                              const float* __restrict__ r1,
                                              const float* __restrict__ w2,
                                              const float* __restrict__ b2,
                                              const float* __restrict__ r2,
                                              _Float16* __restrict__ BT1,
                                              _Float16* __restrict__ BT2) {
    int bx = blockIdx.x, by = blockIdx.y;
    if (bx == 0) {
        if (by == 0) csr_body(dst, starts, elist);
        return;
    }
    int pbx = bx - 1, o0 = by * 64;
    if (pbx < NC1)
        packT_body(w1, b1, r1, BT1, pbx * 64, o0, K1, 2048, 2112, 6, 63, 16384);
    else
        packT_body(w2, b2, r2, BT2, (pbx - NC1) * 64, o0, K2, 8192, 8448, 8, 255, 65536);
}

// ---------------- conv1 staging: barrier-free, vectorized ----------------
__global__ __launch_bounds__(64) void s1_k(const float* __restrict__ x,
                                           const float* __restrict__ ea,
                                           const int* __restrict__ src,
                                           const int* __restrict__ starts,
                                           const int* __restrict__ elist,
                                           _Float16* __restrict__ S) {
    int n = blockIdx.x, t = threadIdx.x;
    int cg = t & 7, kg = t >> 3;
    int i0 = cg * 8;
    float acc[5][8] = {};
    int e0 = starts[n], e1 = starts[n + 1];
    for (int ie = e0; ie < e1; ++ie) {
        int e = elist[ie];
        int sn = src[e];
        float4 f0 = *(const float4*)&x[sn * 64 + i0];
        float4 f1 = *(const float4*)&x[sn * 64 + i0 + 4];
        float xv[8] = {f0.x, f0.y, f0.z, f0.w, f1.x, f1.y, f1.z, f1.w};
#pragma unroll
        for (int j = 0; j < 4; ++j) {
            float va = ea[e * 32 + kg + 8 * j];
#pragma unroll
            for (int c = 0; c < 8; ++c) acc[j][c] += va * xv[c];
        }
        if (kg == 0) {
#pragma unroll
            for (int c = 0; c < 8; ++c) acc[4][c] += xv[c];   // k=32, ea'=1
        }
    }
    _Float16* row = S + (size_t)n * K1;
#pragma unroll
    for (int j = 0; j < 4; ++j) {
        int k = kg + 8 * j;
        half8v o;
#pragma unroll
        for (int c = 0; c < 8; ++c) o[c] = (_Float16)acc[j][c];
        *(half8v*)&row[k * 64 + i0] = o;
    }
    if (kg == 0) {
        half8v o;
#pragma unroll
        for (int c = 0; c < 8; ++c) o[c] = (_Float16)acc[4][c];
        *(half8v*)&row[32 * 64 + i0] = o;
    }
    if (kg == 1) {
        float4 f0 = *(const float4*)&x[n * 64 + i0];
        float4 f1 = *(const float4*)&x[n * 64 + i0 + 4];
        half8v o;
        o[0] = (_Float16)f0.x; o[1] = (_Float16)f0.y; o[2] = (_Float16)f0.z; o[3] = (_Float16)f0.w;
        o[4] = (_Float16)f1.x; o[5] = (_Float16)f1.y; o[6] = (_Float16)f1.z; o[7] = (_Float16)f1.w;
        *(half8v*)&row[2112 + i0] = o;
    }
}

// ---------------- async global->LDS helper ----------------
__device__ __forceinline__ void async_copy16(const void* g, void* l) {
    __builtin_amdgcn_global_load_lds(
        (__attribute__((address_space(1))) unsigned int*)(g),
        (__attribute__((address_space(3))) unsigned int*)(l), 16, 0, 0);
}

// ---------------- conv1 GEMM: 4-wave 128x128, fp16 partials (proven r7 path) ----------------
__global__ __launch_bounds__(256, 3) void gemm_f16(const _Float16* __restrict__ A,
                                                   const _Float16* __restrict__ BT,
                                                   _Float16* __restrict__ Cpart,
                                                   int K, int NC, int Z) {
    __shared__ _Float16 lds[17408];     // 34 KB: staging 2x(128x64); epilogue 4x(64x68)
    _Float16* As = lds;
    _Float16* Bs = lds + 128 * 64;
    int tid = threadIdx.x;
    int w = tid >> 6, l = tid & 63;
    int mt = blockIdx.y, nt = blockIdx.x, z = blockIdx.z;
    int c0 = z * NC / Z, c1 = (z + 1) * NC / Z;
    int k0 = c0 * 64;
    int wm = w & 1, wn = w >> 1;

    int lr = l >> 3, lc = l & 7;
    int gc = lc ^ lr;
    const _Float16* gA0 = A  + (size_t)(mt * 128 + w * 32 + lr) * K + k0 + gc * 8;
    const _Float16* gB0 = BT + (size_t)(nt * 128 + w * 32 + lr) * K + k0 + gc * 8;

    int lm = l & 15, q4 = l >> 4;
    int sw = lm & 7;

    floatx4 acc[4][4] = {};

    for (int s = c0; s < c1; ++s) {
#pragma unroll
        for (int q = 0; q < 4; ++q) {
            async_copy16(gA0 + (size_t)q * 8 * K, As + (w * 32 + q * 8) * 64);
            async_copy16(gB0 + (size_t)q * 8 * K, Bs + (w * 32 + q * 8) * 64);
        }
        gA0 += 64; gB0 += 64;
        __syncthreads();
#pragma unroll
        for (int kw = 0; kw < 2; ++kw) {
            int ck = ((kw * 4 + q4) ^ sw) * 8;
            half8v af[4], bf[4];
#pragma unroll
            for (int i = 0; i < 4; ++i)
                af[i] = *(const half8v*)&As[(wm * 64 + i * 16 + lm) * 64 + ck];
#pragma unroll
            for (int j = 0; j < 4; ++j)
                bf[j] = *(const half8v*)&Bs[(wn * 64 + j * 16 + lm) * 64 + ck];
#pragma unroll
            for (int i = 0; i < 4; ++i)
#pragma unroll
                for (int j = 0; j < 4; ++j)
                    acc[i][j] = __builtin_amdgcn_mfma_f32_16x16x32_f16(af[i], bf[j], acc[i][j], 0, 0, 0);
        }
        __syncthreads();
    }

    // coalesced epilogue via LDS
    _Float16* ep = lds + w * 4352;      // 64*68 halves
#pragma unroll
    for (int i = 0; i < 4; ++i)
#pragma unroll
        for (int j = 0; j < 4; ++j)
#pragma unroll
            for (int r = 0; r < 4; ++r)
                ep[(i * 16 + q4 * 4 + r) * 68 + j * 16 + lm] = (_Float16)acc[i][j][r];
    __syncthreads();
    _Float16* Cp = Cpart + (size_t)z * (N_NODES * HH);
    int row8 = l >> 3, colg = (l & 7) * 8;
    int gm0 = mt * 128 + wm * 64, gn0 = nt * 128 + wn * 64;
#pragma unroll
    for (int i8 = 0; i8 < 8; ++i8) {
        int rr = i8 * 8 + row8;
        half4v lo = *(const half4v*)&ep[rr * 68 + colg];
        half4v hi = *(const half4v*)&ep[rr * 68 + colg + 4];
        half8v v;
        v[0] = lo[0]; v[1] = lo[1]; v[2] = lo[2]; v[3] = lo[3];
        v[4] = hi[0]; v[5] = hi[1]; v[6] = hi[2]; v[7] = hi[3];
        *(half8v*)&Cp[(size_t)(gm0 + rr) * HH + gn0 + colg] = v;
    }
}

// ---------------- conv1 epilogue: split-K reduce + bias1 + relu -> h fp16 ----------------
__global__ __launch_bounds__(256) void hep_k(const _Float16* __restrict__ Cp,
                                             const float* __restrict__ bias,
                                             _Float16* __restrict__ h) {
    int idx = (blockIdx.x * 256 + threadIdx.x) * 8;
    float a[8] = {};
#pragma unroll
    for (int zz = 0; zz < NSL1; ++zz) {
        half8v v = *(const half8v*)(Cp + (size_t)zz * (N_NODES * HH) + idx);
#pragma unroll
        for (int j = 0; j < 8; ++j) a[j] += (float)v[j];
    }
    int col = idx & 255;
    half8v o;
#pragma unroll
    for (int j = 0; j < 8; ++j) o[j] = (_Float16)fmaxf(a[j] + bias[col + j], 0.f);
    *(half8v*)(h + idx) = o;
}

// ---------------- SG staging: graph-pooled lifted matrix, one block per graph ----------------
// Pool commutes with the conv2 GEMM (no activation between conv2 and mean-pool):
// pooled_sum[g,:] = (sum_{n in g} S2[n,:]) @ W2aug = SG[g,:] @ W2aug.
// SG[g, k*256+i] = sum_{e: dst in g} ea'[e,k] * h[src[e], i]   (ea'[.,32] = 1)
// SG[g, 8448+i]  = sum_{n in g} h[n,i]                          (root2 augment)
// Nodes are batch-sorted and elist is dst-grouped, so graph edges are contiguous.
__global__ __launch_bounds__(256) void sg_k(const _Float16* __restrict__ h,
                                            const float* __restrict__ ea,
                                            const int* __restrict__ src,
                                            const int* __restrict__ starts,
                                            const int* __restrict__ elist,
                                            const int* __restrict__ batch,
                                            _Float16* __restrict__ SG) {
    int g = blockIdx.x, t = threadIdx.x;
    __shared__ int bnds[2];
    __shared__ int sl[CHUNK];
    __shared__ float eaS[CHUNK * 32];       // 8 KB
    __shared__ _Float16 hS[CHUNK * 256];    // 32 KB
    if (t < 2) {
        int target = g + t;
        int lo = 0, hi = N_NODES;
        while (lo < hi) { int mid = (lo + hi) >> 1; if (batch[mid] < target) lo = mid + 1; else hi = mid; }
        bnds[t] = lo;
    }
    __syncthreads();
    int nlo = bnds[0], nhi = bnds[1];
    int e0 = starts[nlo], e1 = starts[nhi];
    float acc[33];
#pragma unroll
    for (int k = 0; k < 33; ++k) acc[k] = 0.f;
    for (int base = e0; base < e1; base += CHUNK) {
        int ne = min(CHUNK, e1 - base);
        if (t < ne) { int e = elist[base + t]; sl[t] = src[e]; }
        __syncthreads();
        for (int j = t; j < ne * 32; j += 256) {
            int e = elist[base + (j >> 5)];
            eaS[j] = ea[e * 32 + (j & 31)];
        }
        for (int ie = 0; ie < ne; ++ie)
            hS[ie * 256 + t] = h[(size_t)sl[ie] * 256 + t];
        __syncthreads();
        for (int ie = 0; ie < ne; ++ie) {
            float hv = (float)hS[ie * 256 + t];
            const float* er = &eaS[ie * 32];
#pragma unroll 8
            for (int k = 0; k < 32; ++k) acc[k] += er[k] * hv;
            acc[32] += hv;
        }
        __syncthreads();    // protect LDS reuse across chunks
    }
    float aug = 0.f;
    for (int n = nlo; n < nhi; ++n) aug += (float)h[(size_t)n * 256 + t];
    _Float16* row = SG + (size_t)g * K2;
#pragma unroll
    for (int k = 0; k < 33; ++k) row[k * 256 + t] = (_Float16)acc[k];
    row[8448 + t] = (_Float16)aug;
}

// ---------------- pooled conv2 mini-GEMM: [256xK2] @ BT2^T, split-K, f32 partials ----------------
// Same staging/MFMA algebra as gemm_f16; direct f32 epilogue (no LDS pass, no atomics).
__global__ __launch_bounds__(256, 3) void gemm_sg(const _Float16* __restrict__ A,
                                                  const _Float16* __restrict__ BT,
                                                  float* __restrict__ Cp,
                                                  int K, int NC, int Z) {
    __shared__ _Float16 lds[16384];     // As 128x64 + Bs 128x64
    _Float16* As = lds;
    _Float16* Bs = lds + 128 * 64;
    int tid = threadIdx.x;
    int w = tid >> 6, l = tid & 63;
    int mt = blockIdx.y, nt = blockIdx.x, z = blockIdx.z;
    int c0 = z * NC / Z, c1 = (z + 1) * NC / Z;
    int k0 = c0 * 64;
    int wm = w & 1, wn = w >> 1;

    int lr = l >> 3, lc = l & 7;
    int gc = lc ^ lr;
    const _Float16* gA0 = A  + (size_t)(mt * 128 + w * 32 + lr) * K + k0 + gc * 8;
    const _Float16* gB0 = BT + (size_t)(nt * 128 + w * 32 + lr) * K + k0 + gc * 8;

    int lm = l & 15, q4 = l >> 4;
    int sw = lm & 7;

    floatx4 acc[4][4] = {};

    for (int s = c0; s < c1; ++s) {
#pragma unroll
        for (int q = 0; q < 4; ++q) {
            async_copy16(gA0 + (size_t)q * 8 * K, As + (w * 32 + q * 8) * 64);
            async_copy16(gB0 + (size_t)q * 8 * K, Bs + (w * 32 + q * 8) * 64);
        }
        gA0 += 64; gB0 += 64;
        __syncthreads();
#pragma unroll
        for (int kw = 0; kw < 2; ++kw) {
            int ck = ((kw * 4 + q4) ^ sw) * 8;
            half8v af[4], bf[4];
#pragma unroll
            for (int i = 0; i < 4; ++i)
                af[i] = *(const half8v*)&As[(wm * 64 + i * 16 + lm) * 64 + ck];
#pragma unroll
            for (int j = 0; j < 4; ++j)
                bf[j] = *(const half8v*)&Bs[(wn * 64 + j * 16 + lm) * 64 + ck];
#pragma unroll
            for (int i = 0; i < 4; ++i)
#pragma unroll
                for (int j = 0; j < 4; ++j)
                    acc[i][j] = __builtin_amdgcn_mfma_f32_16x16x32_f16(af[i], bf[j], acc[i][j], 0, 0, 0);
        }
        __syncthreads();
    }

    float* C = Cp + (size_t)z * (N_GRAPHS * HH);
    int gm0 = mt * 128 + wm * 64, gn0 = nt * 128 + wn * 64;
#pragma unroll
    for (int i = 0; i < 4; ++i)
#pragma unroll
        for (int j = 0; j < 4; ++j)
#pragma unroll
            for (int r = 0; r < 4; ++r)
                C[(size_t)(gm0 + i * 16 + q4 * 4 + r) * HH + gn0 + j * 16 + lm] = acc[i][j][r];
}

// ---------------- readout: reduce partials -> mean + bias2 -> MLP -> sigmoid ----------------
__global__ __launch_bounds__(256) void readout_k(const float* __restrict__ CpS,
                                                 const int* __restrict__ batch,
                                                 const float* __restrict__ bias2,
                                                 const float* __restrict__ l1w,
                                                 const float* __restrict__ l1b,
                                                 const float* __restrict__ l2w,
                                                 const float* __restrict__ l2b,
                                                 float* __restrict__ out) {
    int g = blockIdx.x, t = threadIdx.x;
    __shared__ int bnds[2];
    __shared__ float sp[256];
    __shared__ float sz[128];
    if (t < 2) {
        int target = g + t;
        int lo = 0, hi = N_NODES;
        while (lo < hi) { int mid = (lo + hi) >> 1; if (batch[mid] < target) lo = mid + 1; else hi = mid; }
        bnds[t] = lo;
    }
    __syncthreads();
    int lo = bnds[0], hi = bnds[1];
    float s = 0.f;
#pragma unroll
    for (int zz = 0; zz < NSL3; ++zz)
        s += CpS[(size_t)zz * (N_GRAPHS * HH) + g * 256 + t];
    sp[t] = (hi > lo) ? (s / (float)(hi - lo) + bias2[t]) : 0.f;
    __syncthreads();
    if (t < 128) {
        float a = l1b[t];
#pragma unroll 8
        for (int i = 0; i < 256; ++i) a += sp[i] * l1w[i * 128 + t];
        sz[t] = fmaxf(a, 0.f) * l2w[t];
    }
    __syncthreads();
    for (int ss = 64; ss > 0; ss >>= 1) {
        if (t < ss) sz[t] += sz[t + ss];
        __syncthreads();
    }
    if (t == 0) {
        float zz = sz[0] + l2b[0];
        out[g] = 1.0f / (1.0f + expf(-zz));
    }
}

extern "C" void kernel_launch(void* const* d_in, const int* in_sizes, int n_in,
                              void* d_out, int out_size, void* d_ws, size_t ws_size,
                              hipStream_t stream) {
    const float* x       = (const float*)d_in[0];
    const int*   ei      = (const int*)d_in[1];
    const float* ea      = (const float*)d_in[2];
    const int*   batch   = (const int*)d_in[3];
    const float* nn1_w   = (const float*)d_in[4];
    const float* nn1_b   = (const float*)d_in[5];
    const float* root1_w = (const float*)d_in[6];
    const float* bias1   = (const float*)d_in[7];
    const float* nn2_w   = (const float*)d_in[8];
    const float* nn2_b   = (const float*)d_in[9];
    const float* root2_w = (const float*)d_in[10];
    const float* bias2   = (const float*)d_in[11];
    const float* lin1_w  = (const float*)d_in[12];
    const float* lin1_b  = (const float*)d_in[13];
    const float* lin2_w  = (const float*)d_in[14];
    const float* lin2_b  = (const float*)d_in[15];
    float* out = (float*)d_out;
    float* ws  = (float*)d_ws;

    _Float16* S   = (_Float16*)(ws + OFF_S);    // S1, then SG (time-disjoint)
    _Float16* BT1 = (_Float16*)(ws + OFF_BT1);
    _Float16* BT2 = (_Float16*)(ws + OFF_BT2);
    _Float16* Cp  = (_Float16*)(ws + OFF_CP);   // conv1 fp16 partials
    float*    CpS = ws + OFF_CP;                // then f32 partials for mini-GEMM (time-disjoint)
    _Float16* h   = (_Float16*)(ws + OFF_H);
    int* ip     = (int*)(ws + OFF_INT);
    int* starts = ip;            // 4097
    int* elist  = ip + 4100;     // 8192

    const int* srcv = ei;
    const int* dstv = ei + N_EDGES;

    // 1) CSR + weight pack
    prep_k<<<dim3(1 + NC1 + NC2, 4), 256, 0, stream>>>(
        dstv, starts, elist, nn1_w, nn1_b, root1_w, nn2_w, nn2_b, root2_w, BT1, BT2);

    // 2) conv1 staging: S1 [4096 x 2176] fp16
    s1_k<<<4096, 64, 0, stream>>>(x, ea, srcv, starts, elist, S);

    // 3) conv1 GEMM, split-K=8, fp16 partials
    gemm_f16<<<dim3(2, 32, NSL1), 256, 0, stream>>>(S, BT1, Cp, K1, NC1, NSL1);

    // 4) reduce + bias1 + relu -> h fp16
    hep_k<<<512, 256, 0, stream>>>(Cp, bias1, h);

    // 5) graph-pooled conv2 staging: SG [256 x 8704] fp16 (replaces S2, 16x smaller M)
    sg_k<<<N_GRAPHS, 256, 0, stream>>>(h, ea, srcv, starts, elist, batch, S);

    // 6) pooled conv2 mini-GEMM: [256 x 8704] @ W2aug -> f32 partials, split-K=32
    gemm_sg<<<dim3(2, 2, NSL3), 256, 0, stream>>>(S, BT2, CpS, K2, NC2, NSL3);

    // 7) reduce partials + mean + bias2 + MLP + sigmoid
    readout_k<<<N_GRAPHS, 256, 0, stream>>>(CpS, batch, bias2,
                                            lin1_w, lin1_b, lin2_w, lin2_b, out);
}

// Round 5
// 176.158 us; speedup vs baseline: 1.6086x; 1.6086x over previous
//
#include <hip/hip_runtime.h>
#include <math.h>

#define N_NODES 4096
#define N_EDGES 8192
#define N_GRAPHS 256
#define D_NODE 64
#define D_EDGE 32
#define HH 256

#define K1 2176   // 33*64 (edge-MLP + nn_b rows) + 64 (x augment for root1)
#define K2 8704   // 33*256 + 256 (h augment for root2)
#define NC1 34
#define NC2 136
#define NSL1 8    // split-K slices conv1
#define NSL3 32   // split-K slices pooled conv2 mini-GEMM
#define CHUNK 128 // sg_k edge chunk (LDS-staged ids)

typedef _Float16 half8v __attribute__((ext_vector_type(8)));
typedef _Float16 half4v __attribute__((ext_vector_type(4)));
typedef float floatx4 __attribute__((ext_vector_type(4)));

// ---------------- workspace layout (float offsets) ----------------
static const size_t OFF_S    = 0;              // S1 fp16 [4096x2176]; later SG fp16 [256x8704] (time-disjoint)
static const size_t OFF_BT1  = 17825792;       // BT1 fp16: 256 x 2176 halves
static const size_t OFF_BT2  = 18104320;       // BT2 fp16: 256 x 8704 halves
static const size_t OFF_CP   = 19218432;       // Cpart fp16 (conv1, 8 slices); later CpS f32 [32][256][256]
static const size_t OFF_H    = 25509888;       // h fp16: 524,288 floats
static const size_t OFF_INT  = 26034176;       // starts[4097] + pad + elist[8192]

// ---------------- prep: CSR build (block 0) + weight pack (other blocks) ----------------
__device__ void csr_body(const int* __restrict__ dst,
                         int* __restrict__ starts,
                         int* __restrict__ elist) {
    __shared__ int cnt[4096];
    __shared__ int ps[256];
    int t = threadIdx.x;
#pragma unroll
    for (int i = 0; i < 16; ++i) cnt[t * 16 + i] = 0;
    __syncthreads();
#pragma unroll
    for (int i = 0; i < 32; ++i) atomicAdd(&cnt[dst[i * 256 + t]], 1);
    __syncthreads();
    int v[16]; int s = 0;
#pragma unroll
    for (int i = 0; i < 16; ++i) { v[i] = cnt[t * 16 + i]; s += v[i]; }
    ps[t] = s;
    __syncthreads();
    for (int off = 1; off < 256; off <<= 1) {
        int tv = (t >= off) ? ps[t - off] : 0;
        __syncthreads();
        ps[t] += tv;
        __syncthreads();
    }
    int excl = ps[t] - s;
#pragma unroll
    for (int i = 0; i < 16; ++i) {
        starts[t * 16 + i] = excl;
        cnt[t * 16 + i] = excl;       // becomes cursor
        excl += v[i];
    }
    if (t == 255) starts[4096] = excl;
    __syncthreads();
#pragma unroll
    for (int i = 0; i < 32; ++i) {
        int e = i * 256 + t;
        int d = dst[e];
        int p = atomicAdd(&cnt[d], 1);
        elist[p] = e;
    }
}

__device__ void packT_body(const float* __restrict__ w,
                           const float* __restrict__ b,
                           const float* __restrict__ rw,
                           _Float16* __restrict__ BT,
                           int kk0, int o0, int K,
                           int wlim, int blim, int wshift, int wmask, int wrow) {
    __shared__ float T[64][65];
    int t = threadIdx.x;
    int ol = t & 63, kb = t >> 6;
#pragma unroll
    for (int p = 0; p < 16; ++p) {
        int kl = p * 4 + kb;
        int kk = kk0 + kl, o = o0 + ol;
        float v;
        if (kk < wlim)      v = w[(kk >> wshift) * wrow + (kk & wmask) * 256 + o];
        else if (kk < blim) v = b[(kk - wlim) * 256 + o];
        else                v = rw[(kk - blim) * 256 + o];
        T[kl][ol] = v;
    }
    __syncthreads();
    int kl2 = t & 63, ob = t >> 6;
#pragma unroll
    for (int p = 0; p < 16; ++p) {
        int ol2 = p * 4 + ob;
        BT[(size_t)(o0 + ol2) * K + kk0 + kl2] = (_Float16)T[kl2][ol2];
    }
}

__global__ __launch_bounds__(256) void prep_k(const int* __restrict__ dst,
                                              int* __restrict__ starts,
                                              int* __restrict__ elist,
                                              const float* __restrict__ w1,
                                              const float* __restrict__ b1,
                                              const float* __restrict__ r1,
                                              const float* __restrict__ w2,
                                              const float* __restrict__ b2,
                                              const float* __restrict__ r2,
                                              _Float16* __restrict__ BT1,
                                              _Float16* __restrict__ BT2) {
    int bx = blockIdx.x, by = blockIdx.y;
    if (bx == 0) {
        if (by == 0) csr_body(dst, starts, elist);
        return;
    }
    int pbx = bx - 1, o0 = by * 64;
    if (pbx < NC1)
        packT_body(w1, b1, r1, BT1, pbx * 64, o0, K1, 2048, 2112, 6, 63, 16384);
    else
        packT_body(w2, b2, r2, BT2, (pbx - NC1) * 64, o0, K2, 8192, 8448, 8, 255, 65536);
}

// ---------------- conv1 staging: barrier-free, vectorized ----------------
__global__ __launch_bounds__(64) void s1_k(const float* __restrict__ x,
                                           const float* __restrict__ ea,
                                           const int* __restrict__ src,
                                           const int* __restrict__ starts,
                                           const int* __restrict__ elist,
                                           _Float16* __restrict__ S) {
    int n = blockIdx.x, t = threadIdx.x;
    int cg = t & 7, kg = t >> 3;
    int i0 = cg * 8;
    float acc[5][8] = {};
    int e0 = starts[n], e1 = starts[n + 1];
    for (int ie = e0; ie < e1; ++ie) {
        int e = elist[ie];
        int sn = src[e];
        float4 f0 = *(const float4*)&x[sn * 64 + i0];
        float4 f1 = *(const float4*)&x[sn * 64 + i0 + 4];
        float xv[8] = {f0.x, f0.y, f0.z, f0.w, f1.x, f1.y, f1.z, f1.w};
#pragma unroll
        for (int j = 0; j < 4; ++j) {
            float va = ea[e * 32 + kg + 8 * j];
#pragma unroll
            for (int c = 0; c < 8; ++c) acc[j][c] += va * xv[c];
        }
        if (kg == 0) {
#pragma unroll
            for (int c = 0; c < 8; ++c) acc[4][c] += xv[c];   // k=32, ea'=1
        }
    }
    _Float16* row = S + (size_t)n * K1;
#pragma unroll
    for (int j = 0; j < 4; ++j) {
        int k = kg + 8 * j;
        half8v o;
#pragma unroll
        for (int c = 0; c < 8; ++c) o[c] = (_Float16)acc[j][c];
        *(half8v*)&row[k * 64 + i0] = o;
    }
    if (kg == 0) {
        half8v o;
#pragma unroll
        for (int c = 0; c < 8; ++c) o[c] = (_Float16)acc[4][c];
        *(half8v*)&row[32 * 64 + i0] = o;
    }
    if (kg == 1) {
        float4 f0 = *(const float4*)&x[n * 64 + i0];
        float4 f1 = *(const float4*)&x[n * 64 + i0 + 4];
        half8v o;
        o[0] = (_Float16)f0.x; o[1] = (_Float16)f0.y; o[2] = (_Float16)f0.z; o[3] = (_Float16)f0.w;
        o[4] = (_Float16)f1.x; o[5] = (_Float16)f1.y; o[6] = (_Float16)f1.z; o[7] = (_Float16)f1.w;
        *(half8v*)&row[2112 + i0] = o;
    }
}

// ---------------- async global->LDS helper ----------------
__device__ __forceinline__ void async_copy16(const void* g, void* l) {
    __builtin_amdgcn_global_load_lds(
        (__attribute__((address_space(1))) unsigned int*)(g),
        (__attribute__((address_space(3))) unsigned int*)(l), 16, 0, 0);
}

// ---------------- conv1 GEMM: 4-wave 128x128, fp16 partials (proven r7 path) ----------------
__global__ __launch_bounds__(256, 3) void gemm_f16(const _Float16* __restrict__ A,
                                                   const _Float16* __restrict__ BT,
                                                   _Float16* __restrict__ Cpart,
                                                   int K, int NC, int Z) {
    __shared__ _Float16 lds[17408];     // 34 KB: staging 2x(128x64); epilogue 4x(64x68)
    _Float16* As = lds;
    _Float16* Bs = lds + 128 * 64;
    int tid = threadIdx.x;
    int w = tid >> 6, l = tid & 63;
    int mt = blockIdx.y, nt = blockIdx.x, z = blockIdx.z;
    int c0 = z * NC / Z, c1 = (z + 1) * NC / Z;
    int k0 = c0 * 64;
    int wm = w & 1, wn = w >> 1;

    int lr = l >> 3, lc = l & 7;
    int gc = lc ^ lr;
    const _Float16* gA0 = A  + (size_t)(mt * 128 + w * 32 + lr) * K + k0 + gc * 8;
    const _Float16* gB0 = BT + (size_t)(nt * 128 + w * 32 + lr) * K + k0 + gc * 8;

    int lm = l & 15, q4 = l >> 4;
    int sw = lm & 7;

    floatx4 acc[4][4] = {};

    for (int s = c0; s < c1; ++s) {
#pragma unroll
        for (int q = 0; q < 4; ++q) {
            async_copy16(gA0 + (size_t)q * 8 * K, As + (w * 32 + q * 8) * 64);
            async_copy16(gB0 + (size_t)q * 8 * K, Bs + (w * 32 + q * 8) * 64);
        }
        gA0 += 64; gB0 += 64;
        __syncthreads();
#pragma unroll
        for (int kw = 0; kw < 2; ++kw) {
            int ck = ((kw * 4 + q4) ^ sw) * 8;
            half8v af[4], bf[4];
#pragma unroll
            for (int i = 0; i < 4; ++i)
                af[i] = *(const half8v*)&As[(wm * 64 + i * 16 + lm) * 64 + ck];
#pragma unroll
            for (int j = 0; j < 4; ++j)
                bf[j] = *(const half8v*)&Bs[(wn * 64 + j * 16 + lm) * 64 + ck];
#pragma unroll
            for (int i = 0; i < 4; ++i)
#pragma unroll
                for (int j = 0; j < 4; ++j)
                    acc[i][j] = __builtin_amdgcn_mfma_f32_16x16x32_f16(af[i], bf[j], acc[i][j], 0, 0, 0);
        }
        __syncthreads();
    }

    // coalesced epilogue via LDS
    _Float16* ep = lds + w * 4352;      // 64*68 halves
#pragma unroll
    for (int i = 0; i < 4; ++i)
#pragma unroll
        for (int j = 0; j < 4; ++j)
#pragma unroll
            for (int r = 0; r < 4; ++r)
                ep[(i * 16 + q4 * 4 + r) * 68 + j * 16 + lm] = (_Float16)acc[i][j][r];
    __syncthreads();
    _Float16* Cp = Cpart + (size_t)z * (N_NODES * HH);
    int row8 = l >> 3, colg = (l & 7) * 8;
    int gm0 = mt * 128 + wm * 64, gn0 = nt * 128 + wn * 64;
#pragma unroll
    for (int i8 = 0; i8 < 8; ++i8) {
        int rr = i8 * 8 + row8;
        half4v lo = *(const half4v*)&ep[rr * 68 + colg];
        half4v hi = *(const half4v*)&ep[rr * 68 + colg + 4];
        half8v v;
        v[0] = lo[0]; v[1] = lo[1]; v[2] = lo[2]; v[3] = lo[3];
        v[4] = hi[0]; v[5] = hi[1]; v[6] = hi[2]; v[7] = hi[3];
        *(half8v*)&Cp[(size_t)(gm0 + rr) * HH + gn0 + colg] = v;
    }
}

// ---------------- conv1 epilogue: split-K reduce + bias1 + relu -> h fp16 ----------------
__global__ __launch_bounds__(256) void hep_k(const _Float16* __restrict__ Cp,
                                             const float* __restrict__ bias,
                                             _Float16* __restrict__ h) {
    int idx = (blockIdx.x * 256 + threadIdx.x) * 8;
    float a[8] = {};
#pragma unroll
    for (int zz = 0; zz < NSL1; ++zz) {
        half8v v = *(const half8v*)(Cp + (size_t)zz * (N_NODES * HH) + idx);
#pragma unroll
        for (int j = 0; j < 8; ++j) a[j] += (float)v[j];
    }
    int col = idx & 255;
    half8v o;
#pragma unroll
    for (int j = 0; j < 8; ++j) o[j] = (_Float16)fmaxf(a[j] + bias[col + j], 0.f);
    *(half8v*)(h + idx) = o;
}

// ---------------- SG staging: graph-pooled lifted matrix, (graph x k-group) grid ----------------
// Pool commutes with the conv2 GEMM (no activation between conv2 and mean-pool):
// pooled_sum[g,:] = (sum_{n in g} S2[n,:]) @ W2aug = SG[g,:] @ W2aug.
// SG[g, k*256+i] = sum_{e: dst in g} ea'[e,k] * h[src[e], i]   (ea'[.,32] = 1)
// SG[g, 8448+i]  = sum_{n in g} h[n,i]                          (root2 augment)
// Grid (256 graphs, 9 kgroups): kg<8 owns k=kg*4..+3; kg==8 owns k=32 + augment.
// Thread t owns column i=t. 2304 blocks -> ~9 blocks/CU TLP hides gather latency
// (round-4's 1-block-per-graph version was latency-serialized at 129 us).
// Per-accumulator FMA order identical to round 4 -> bit-identical numerics.
__global__ __launch_bounds__(256) void sg_k(const _Float16* __restrict__ h,
                                            const float* __restrict__ ea,
                                            const int* __restrict__ src,
                                            const int* __restrict__ starts,
                                            const int* __restrict__ elist,
                                            const int* __restrict__ batch,
                                            _Float16* __restrict__ SG) {
    int g = blockIdx.x, kg = blockIdx.y, t = threadIdx.x;
    __shared__ int bnds[2];
    __shared__ int sl[CHUNK];
    __shared__ int el[CHUNK];
    if (t < 2) {
        int target = g + t;
        int lo = 0, hi = N_NODES;
        while (lo < hi) { int mid = (lo + hi) >> 1; if (batch[mid] < target) lo = mid + 1; else hi = mid; }
        bnds[t] = lo;
    }
    __syncthreads();
    int nlo = bnds[0], nhi = bnds[1];
    int e0 = starts[nlo], e1 = starts[nhi];
    _Float16* row = SG + (size_t)g * K2;

    if (kg < 8) {
        float acc[4] = {};
        for (int base = e0; base < e1; base += CHUNK) {
            int ne = min(CHUNK, e1 - base);
            if (t < ne) { int e = elist[base + t]; el[t] = e; sl[t] = src[e]; }
            __syncthreads();
            for (int ie = 0; ie < ne; ++ie) {
                float hv = (float)h[(size_t)sl[ie] * 256 + t];
                float4 ev = *(const float4*)&ea[(size_t)el[ie] * 32 + kg * 4];
                acc[0] += ev.x * hv; acc[1] += ev.y * hv;
                acc[2] += ev.z * hv; acc[3] += ev.w * hv;
            }
            __syncthreads();
        }
#pragma unroll
        for (int j = 0; j < 4; ++j)
            row[(kg * 4 + j) * 256 + t] = (_Float16)acc[j];
    } else {
        float a32 = 0.f;
        for (int base = e0; base < e1; base += CHUNK) {
            int ne = min(CHUNK, e1 - base);
            if (t < ne) sl[t] = src[elist[base + t]];
            __syncthreads();
            for (int ie = 0; ie < ne; ++ie)
                a32 += (float)h[(size_t)sl[ie] * 256 + t];
            __syncthreads();
        }
        float aug = 0.f;
        for (int n = nlo; n < nhi; ++n) aug += (float)h[(size_t)n * 256 + t];
        row[32 * 256 + t] = (_Float16)a32;
        row[8448 + t] = (_Float16)aug;
    }
}

// ---------------- pooled conv2 mini-GEMM: [256xK2] @ BT2^T, split-K, f32 partials ----------------
__global__ __launch_bounds__(256, 3) void gemm_sg(const _Float16* __restrict__ A,
                                                  const _Float16* __restrict__ BT,
                                                  float* __restrict__ Cp,
                                                  int K, int NC, int Z) {
    __shared__ _Float16 lds[16384];     // As 128x64 + Bs 128x64
    _Float16* As = lds;
    _Float16* Bs = lds + 128 * 64;
    int tid = threadIdx.x;
    int w = tid >> 6, l = tid & 63;
    int mt = blockIdx.y, nt = blockIdx.x, z = blockIdx.z;
    int c0 = z * NC / Z, c1 = (z + 1) * NC / Z;
    int k0 = c0 * 64;
    int wm = w & 1, wn = w >> 1;

    int lr = l >> 3, lc = l & 7;
    int gc = lc ^ lr;
    const _Float16* gA0 = A  + (size_t)(mt * 128 + w * 32 + lr) * K + k0 + gc * 8;
    const _Float16* gB0 = BT + (size_t)(nt * 128 + w * 32 + lr) * K + k0 + gc * 8;

    int lm = l & 15, q4 = l >> 4;
    int sw = lm & 7;

    floatx4 acc[4][4] = {};

    for (int s = c0; s < c1; ++s) {
#pragma unroll
        for (int q = 0; q < 4; ++q) {
            async_copy16(gA0 + (size_t)q * 8 * K, As + (w * 32 + q * 8) * 64);
            async_copy16(gB0 + (size_t)q * 8 * K, Bs + (w * 32 + q * 8) * 64);
        }
        gA0 += 64; gB0 += 64;
        __syncthreads();
#pragma unroll
        for (int kw = 0; kw < 2; ++kw) {
            int ck = ((kw * 4 + q4) ^ sw) * 8;
            half8v af[4], bf[4];
#pragma unroll
            for (int i = 0; i < 4; ++i)
                af[i] = *(const half8v*)&As[(wm * 64 + i * 16 + lm) * 64 + ck];
#pragma unroll
            for (int j = 0; j < 4; ++j)
                bf[j] = *(const half8v*)&Bs[(wn * 64 + j * 16 + lm) * 64 + ck];
#pragma unroll
            for (int i = 0; i < 4; ++i)
#pragma unroll
                for (int j = 0; j < 4; ++j)
                    acc[i][j] = __builtin_amdgcn_mfma_f32_16x16x32_f16(af[i], bf[j], acc[i][j], 0, 0, 0);
        }
        __syncthreads();
    }

    float* C = Cp + (size_t)z * (N_GRAPHS * HH);
    int gm0 = mt * 128 + wm * 64, gn0 = nt * 128 + wn * 64;
#pragma unroll
    for (int i = 0; i < 4; ++i)
#pragma unroll
        for (int j = 0; j < 4; ++j)
#pragma unroll
            for (int r = 0; r < 4; ++r)
                C[(size_t)(gm0 + i * 16 + q4 * 4 + r) * HH + gn0 + j * 16 + lm] = acc[i][j][r];
}

// ---------------- readout: reduce partials -> mean + bias2 -> MLP -> sigmoid ----------------
__global__ __launch_bounds__(256) void readout_k(const float* __restrict__ CpS,
                                                 const int* __restrict__ batch,
                                                 const float* __restrict__ bias2,
                                                 const float* __restrict__ l1w,
                                                 const float* __restrict__ l1b,
                                                 const float* __restrict__ l2w,
                                                 const float* __restrict__ l2b,
                                                 float* __restrict__ out) {
    int g = blockIdx.x, t = threadIdx.x;
    __shared__ int bnds[2];
    __shared__ float sp[256];
    __shared__ float sz[128];
    if (t < 2) {
        int target = g + t;
        int lo = 0, hi = N_NODES;
        while (lo < hi) { int mid = (lo + hi) >> 1; if (batch[mid] < target) lo = mid + 1; else hi = mid; }
        bnds[t] = lo;
    }
    __syncthreads();
    int lo = bnds[0], hi = bnds[1];
    float s = 0.f;
#pragma unroll
    for (int zz = 0; zz < NSL3; ++zz)
        s += CpS[(size_t)zz * (N_GRAPHS * HH) + g * 256 + t];
    sp[t] = (hi > lo) ? (s / (float)(hi - lo) + bias2[t]) : 0.f;
    __syncthreads();
    if (t < 128) {
        float a = l1b[t];
#pragma unroll 8
        for (int i = 0; i < 256; ++i) a += sp[i] * l1w[i * 128 + t];
        sz[t] = fmaxf(a, 0.f) * l2w[t];
    }
    __syncthreads();
    for (int ss = 64; ss > 0; ss >>= 1) {
        if (t < ss) sz[t] += sz[t + ss];
        __syncthreads();
    }
    if (t == 0) {
        float zz = sz[0] + l2b[0];
        out[g] = 1.0f / (1.0f + expf(-zz));
    }
}

extern "C" void kernel_launch(void* const* d_in, const int* in_sizes, int n_in,
                              void* d_out, int out_size, void* d_ws, size_t ws_size,
                              hipStream_t stream) {
    const float* x       = (const float*)d_in[0];
    const int*   ei      = (const int*)d_in[1];
    const float* ea      = (const float*)d_in[2];
    const int*   batch   = (const int*)d_in[3];
    const float* nn1_w   = (const float*)d_in[4];
    const float* nn1_b   = (const float*)d_in[5];
    const float* root1_w = (const float*)d_in[6];
    const float* bias1   = (const float*)d_in[7];
    const float* nn2_w   = (const float*)d_in[8];
    const float* nn2_b   = (const float*)d_in[9];
    const float* root2_w = (const float*)d_in[10];
    const float* bias2   = (const float*)d_in[11];
    const float* lin1_w  = (const float*)d_in[12];
    const float* lin1_b  = (const float*)d_in[13];
    const float* lin2_w  = (const float*)d_in[14];
    const float* lin2_b  = (const float*)d_in[15];
    float* out = (float*)d_out;
    float* ws  = (float*)d_ws;

    _Float16* S   = (_Float16*)(ws + OFF_S);    // S1, then SG (time-disjoint)
    _Float16* BT1 = (_Float16*)(ws + OFF_BT1);
    _Float16* BT2 = (_Float16*)(ws + OFF_BT2);
    _Float16* Cp  = (_Float16*)(ws + OFF_CP);   // conv1 fp16 partials
    float*    CpS = ws + OFF_CP;                // then f32 partials for mini-GEMM (time-disjoint)
    _Float16* h   = (_Float16*)(ws + OFF_H);
    int* ip     = (int*)(ws + OFF_INT);
    int* starts = ip;            // 4097
    int* elist  = ip + 4100;     // 8192

    const int* srcv = ei;
    const int* dstv = ei + N_EDGES;

    // 1) CSR + weight pack
    prep_k<<<dim3(1 + NC1 + NC2, 4), 256, 0, stream>>>(
        dstv, starts, elist, nn1_w, nn1_b, root1_w, nn2_w, nn2_b, root2_w, BT1, BT2);

    // 2) conv1 staging: S1 [4096 x 2176] fp16
    s1_k<<<4096, 64, 0, stream>>>(x, ea, srcv, starts, elist, S);

    // 3) conv1 GEMM, split-K=8, fp16 partials
    gemm_f16<<<dim3(2, 32, NSL1), 256, 0, stream>>>(S, BT1, Cp, K1, NC1, NSL1);

    // 4) reduce + bias1 + relu -> h fp16
    hep_k<<<512, 256, 0, stream>>>(Cp, bias1, h);

    // 5) graph-pooled conv2 staging: SG [256 x 8704] fp16, (graph x kgroup) grid
    sg_k<<<dim3(N_GRAPHS, 9), 256, 0, stream>>>(h, ea, srcv, starts, elist, batch, S);

    // 6) pooled conv2 mini-GEMM: [256 x 8704] @ W2aug -> f32 partials, split-K=32
    gemm_sg<<<dim3(2, 2, NSL3), 256, 0, stream>>>(S, BT2, CpS, K2, NC2, NSL3);

    // 7) reduce partials + mean + bias2 + MLP + sigmoid
    readout_k<<<N_GRAPHS, 256, 0, stream>>>(CpS, batch, bias2,
                                            lin1_w, lin1_b, lin2_w, lin2_b, out);
}

// Round 6
// 173.564 us; speedup vs baseline: 1.6327x; 1.0149x over previous
//
#include <hip/hip_runtime.h>
#include <math.h>

#define N_NODES 4096
#define N_EDGES 8192
#define N_GRAPHS 256
#define D_NODE 64
#define D_EDGE 32
#define HH 256

#define K1 2176   // 33*64 (edge-MLP + nn_b rows) + 64 (x augment for root1)
#define K2 8704   // 33*256 + 256 (h augment for root2)
#define NC1 34
#define NC2 136
#define NSL1 8    // split-K slices conv1
#define NSL3 32   // split-K slices pooled conv2 mini-GEMM
#define CHUNK 128 // sg_k edge chunk (LDS-staged ids)

typedef _Float16 half8v __attribute__((ext_vector_type(8)));
typedef _Float16 half4v __attribute__((ext_vector_type(4)));
typedef float floatx4 __attribute__((ext_vector_type(4)));

// ---------------- workspace layout (float offsets) ----------------
static const size_t OFF_S    = 0;              // S1 fp16 [4096x2176]; later SG fp16 [256x8704] (time-disjoint)
static const size_t OFF_BT1  = 17825792;       // BT1 fp16: 256 x 2176 halves
static const size_t OFF_BT2  = 18104320;       // BT2 fp16: 256 x 8704 halves
static const size_t OFF_CP   = 19218432;       // Cpart fp16 (conv1, 8 slices); later CpS f32 [32][256][256]
static const size_t OFF_H    = 25509888;       // h fp16: 524,288 floats
static const size_t OFF_INT  = 26034176;       // starts[4097] + pad + elist[8192]

// ---------------- prep: CSR build (block 0) + weight pack (other blocks) ----------------
__device__ void csr_body(const int* __restrict__ dst,
                         int* __restrict__ starts,
                         int* __restrict__ elist) {
    __shared__ int cnt[4096];
    __shared__ int ps[256];
    int t = threadIdx.x;
#pragma unroll
    for (int i = 0; i < 16; ++i) cnt[t * 16 + i] = 0;
    __syncthreads();
#pragma unroll
    for (int i = 0; i < 32; ++i) atomicAdd(&cnt[dst[i * 256 + t]], 1);
    __syncthreads();
    int v[16]; int s = 0;
#pragma unroll
    for (int i = 0; i < 16; ++i) { v[i] = cnt[t * 16 + i]; s += v[i]; }
    ps[t] = s;
    __syncthreads();
    for (int off = 1; off < 256; off <<= 1) {
        int tv = (t >= off) ? ps[t - off] : 0;
        __syncthreads();
        ps[t] += tv;
        __syncthreads();
    }
    int excl = ps[t] - s;
#pragma unroll
    for (int i = 0; i < 16; ++i) {
        starts[t * 16 + i] = excl;
        cnt[t * 16 + i] = excl;       // becomes cursor
        excl += v[i];
    }
    if (t == 255) starts[4096] = excl;
    __syncthreads();
#pragma unroll
    for (int i = 0; i < 32; ++i) {
        int e = i * 256 + t;
        int d = dst[e];
        int p = atomicAdd(&cnt[d], 1);
        elist[p] = e;
    }
}

__device__ void packT_body(const float* __restrict__ w,
                           const float* __restrict__ b,
                           const float* __restrict__ rw,
                           _Float16* __restrict__ BT,
                           int kk0, int o0, int K,
                           int wlim, int blim, int wshift, int wmask, int wrow) {
    __shared__ float T[64][65];
    int t = threadIdx.x;
    int ol = t & 63, kb = t >> 6;
#pragma unroll
    for (int p = 0; p < 16; ++p) {
        int kl = p * 4 + kb;
        int kk = kk0 + kl, o = o0 + ol;
        float v;
        if (kk < wlim)      v = w[(kk >> wshift) * wrow + (kk & wmask) * 256 + o];
        else if (kk < blim) v = b[(kk - wlim) * 256 + o];
        else                v = rw[(kk - blim) * 256 + o];
        T[kl][ol] = v;
    }
    __syncthreads();
    int kl2 = t & 63, ob = t >> 6;
#pragma unroll
    for (int p = 0; p < 16; ++p) {
        int ol2 = p * 4 + ob;
        BT[(size_t)(o0 + ol2) * K + kk0 + kl2] = (_Float16)T[kl2][ol2];
    }
}

__global__ __launch_bounds__(256) void prep_k(const int* __restrict__ dst,
                                              int* __restrict__ starts,
                                              int* __restrict__ elist,
                                              const float* __restrict__ w1,
                                              const float* __restrict__ b1,
                                              const float* __restrict__ r1,
                                              const float* __restrict__ w2,
                                              const float* __restrict__ b2,
                                              const float* __restrict__ r2,
                                              _Float16* __restrict__ BT1,
                                              _Float16* __restrict__ BT2) {
    int bx = blockIdx.x, by = blockIdx.y;
    if (bx == 0) {
        if (by == 0) csr_body(dst, starts, elist);
        return;
    }
    int pbx = bx - 1, o0 = by * 64;
    if (pbx < NC1)
        packT_body(w1, b1, r1, BT1, pbx * 64, o0, K1, 2048, 2112, 6, 63, 16384);
    else
        packT_body(w2, b2, r2, BT2, (pbx - NC1) * 64, o0, K2, 8192, 8448, 8, 255, 65536);
}

// ---------------- conv1 staging: barrier-free, vectorized ----------------
__global__ __launch_bounds__(64) void s1_k(const float* __restrict__ x,
                                           const float* __restrict__ ea,
                                           const int* __restrict__ src,
                                           const int* __restrict__ starts,
                                           const int* __restrict__ elist,
                                           _Float16* __restrict__ S) {
    int n = blockIdx.x, t = threadIdx.x;
    int cg = t & 7, kg = t >> 3;
    int i0 = cg * 8;
    float acc[5][8] = {};
    int e0 = starts[n], e1 = starts[n + 1];
    for (int ie = e0; ie < e1; ++ie) {
        int e = elist[ie];
        int sn = src[e];
        float4 f0 = *(const float4*)&x[sn * 64 + i0];
        float4 f1 = *(const float4*)&x[sn * 64 + i0 + 4];
        float xv[8] = {f0.x, f0.y, f0.z, f0.w, f1.x, f1.y, f1.z, f1.w};
#pragma unroll
        for (int j = 0; j < 4; ++j) {
            float va = ea[e * 32 + kg + 8 * j];
#pragma unroll
            for (int c = 0; c < 8; ++c) acc[j][c] += va * xv[c];
        }
        if (kg == 0) {
#pragma unroll
            for (int c = 0; c < 8; ++c) acc[4][c] += xv[c];   // k=32, ea'=1
        }
    }
    _Float16* row = S + (size_t)n * K1;
#pragma unroll
    for (int j = 0; j < 4; ++j) {
        int k = kg + 8 * j;
        half8v o;
#pragma unroll
        for (int c = 0; c < 8; ++c) o[c] = (_Float16)acc[j][c];
        *(half8v*)&row[k * 64 + i0] = o;
    }
    if (kg == 0) {
        half8v o;
#pragma unroll
        for (int c = 0; c < 8; ++c) o[c] = (_Float16)acc[4][c];
        *(half8v*)&row[32 * 64 + i0] = o;
    }
    if (kg == 1) {
        float4 f0 = *(const float4*)&x[n * 64 + i0];
        float4 f1 = *(const float4*)&x[n * 64 + i0 + 4];
        half8v o;
        o[0] = (_Float16)f0.x; o[1] = (_Float16)f0.y; o[2] = (_Float16)f0.z; o[3] = (_Float16)f0.w;
        o[4] = (_Float16)f1.x; o[5] = (_Float16)f1.y; o[6] = (_Float16)f1.z; o[7] = (_Float16)f1.w;
        *(half8v*)&row[2112 + i0] = o;
    }
}

// ---------------- async global->LDS helper ----------------
__device__ __forceinline__ void async_copy16(const void* g, void* l) {
    __builtin_amdgcn_global_load_lds(
        (__attribute__((address_space(1))) unsigned int*)(g),
        (__attribute__((address_space(3))) unsigned int*)(l), 16, 0, 0);
}

// ---------------- conv1 GEMM: 4-wave 128x128, fp16 partials (proven r7 path) ----------------
__global__ __launch_bounds__(256, 3) void gemm_f16(const _Float16* __restrict__ A,
                                                   const _Float16* __restrict__ BT,
                                                   _Float16* __restrict__ Cpart,
                                                   int K, int NC, int Z) {
    __shared__ _Float16 lds[17408];     // 34 KB: staging 2x(128x64); epilogue 4x(64x68)
    _Float16* As = lds;
    _Float16* Bs = lds + 128 * 64;
    int tid = threadIdx.x;
    int w = tid >> 6, l = tid & 63;
    int mt = blockIdx.y, nt = blockIdx.x, z = blockIdx.z;
    int c0 = z * NC / Z, c1 = (z + 1) * NC / Z;
    int k0 = c0 * 64;
    int wm = w & 1, wn = w >> 1;

    int lr = l >> 3, lc = l & 7;
    int gc = lc ^ lr;
    const _Float16* gA0 = A  + (size_t)(mt * 128 + w * 32 + lr) * K + k0 + gc * 8;
    const _Float16* gB0 = BT + (size_t)(nt * 128 + w * 32 + lr) * K + k0 + gc * 8;

    int lm = l & 15, q4 = l >> 4;
    int sw = lm & 7;

    floatx4 acc[4][4] = {};

    for (int s = c0; s < c1; ++s) {
#pragma unroll
        for (int q = 0; q < 4; ++q) {
            async_copy16(gA0 + (size_t)q * 8 * K, As + (w * 32 + q * 8) * 64);
            async_copy16(gB0 + (size_t)q * 8 * K, Bs + (w * 32 + q * 8) * 64);
        }
        gA0 += 64; gB0 += 64;
        __syncthreads();
#pragma unroll
        for (int kw = 0; kw < 2; ++kw) {
            int ck = ((kw * 4 + q4) ^ sw) * 8;
            half8v af[4], bf[4];
#pragma unroll
            for (int i = 0; i < 4; ++i)
                af[i] = *(const half8v*)&As[(wm * 64 + i * 16 + lm) * 64 + ck];
#pragma unroll
            for (int j = 0; j < 4; ++j)
                bf[j] = *(const half8v*)&Bs[(wn * 64 + j * 16 + lm) * 64 + ck];
#pragma unroll
            for (int i = 0; i < 4; ++i)
#pragma unroll
                for (int j = 0; j < 4; ++j)
                    acc[i][j] = __builtin_amdgcn_mfma_f32_16x16x32_f16(af[i], bf[j], acc[i][j], 0, 0, 0);
        }
        __syncthreads();
    }

    // coalesced epilogue via LDS
    _Float16* ep = lds + w * 4352;      // 64*68 halves
#pragma unroll
    for (int i = 0; i < 4; ++i)
#pragma unroll
        for (int j = 0; j < 4; ++j)
#pragma unroll
            for (int r = 0; r < 4; ++r)
                ep[(i * 16 + q4 * 4 + r) * 68 + j * 16 + lm] = (_Float16)acc[i][j][r];
    __syncthreads();
    _Float16* Cp = Cpart + (size_t)z * (N_NODES * HH);
    int row8 = l >> 3, colg = (l & 7) * 8;
    int gm0 = mt * 128 + wm * 64, gn0 = nt * 128 + wn * 64;
#pragma unroll
    for (int i8 = 0; i8 < 8; ++i8) {
        int rr = i8 * 8 + row8;
        half4v lo = *(const half4v*)&ep[rr * 68 + colg];
        half4v hi = *(const half4v*)&ep[rr * 68 + colg + 4];
        half8v v;
        v[0] = lo[0]; v[1] = lo[1]; v[2] = lo[2]; v[3] = lo[3];
        v[4] = hi[0]; v[5] = hi[1]; v[6] = hi[2]; v[7] = hi[3];
        *(half8v*)&Cp[(size_t)(gm0 + rr) * HH + gn0 + colg] = v;
    }
}

// ---------------- conv1 epilogue: split-K reduce + bias1 + relu -> h fp16 ----------------
__global__ __launch_bounds__(256) void hep_k(const _Float16* __restrict__ Cp,
                                             const float* __restrict__ bias,
                                             _Float16* __restrict__ h) {
    int idx = (blockIdx.x * 256 + threadIdx.x) * 8;
    float a[8] = {};
#pragma unroll
    for (int zz = 0; zz < NSL1; ++zz) {
        half8v v = *(const half8v*)(Cp + (size_t)zz * (N_NODES * HH) + idx);
#pragma unroll
        for (int j = 0; j < 8; ++j) a[j] += (float)v[j];
    }
    int col = idx & 255;
    half8v o;
#pragma unroll
    for (int j = 0; j < 8; ++j) o[j] = (_Float16)fmaxf(a[j] + bias[col + j], 0.f);
    *(half8v*)(h + idx) = o;
}

// ---------------- SG staging: graph-pooled lifted matrix, (graph x k-group) grid ----------------
// Pool commutes with the conv2 GEMM (no activation between conv2 and mean-pool):
// pooled_sum[g,:] = (sum_{n in g} S2[n,:]) @ W2aug = SG[g,:] @ W2aug.
// SG[g, k*256+i] = sum_{e: dst in g} ea'[e,k] * h[src[e], i]   (ea'[.,32] = 1)
// SG[g, 8448+i]  = sum_{n in g} h[n,i]                          (root2 augment)
// Grid (256 graphs, 9 kgroups); thread t owns column i=t.
// Edge loop is UNROLLED BY 8: 8 independent h-row loads in flight per wait
// (round-5's serial per-edge chain left the kernel latency-bound at 22 us).
// Accumulation order over ie is unchanged -> bit-identical numerics.
__global__ __launch_bounds__(256) void sg_k(const _Float16* __restrict__ h,
                                            const float* __restrict__ ea,
                                            const int* __restrict__ src,
                                            const int* __restrict__ starts,
                                            const int* __restrict__ elist,
                                            const int* __restrict__ batch,
                                            _Float16* __restrict__ SG) {
    int g = blockIdx.x, kg = blockIdx.y, t = threadIdx.x;
    __shared__ int bnds[2];
    __shared__ int sl[CHUNK];
    __shared__ int el[CHUNK];
    if (t < 2) {
        int target = g + t;
        int lo = 0, hi = N_NODES;
        while (lo < hi) { int mid = (lo + hi) >> 1; if (batch[mid] < target) lo = mid + 1; else hi = mid; }
        bnds[t] = lo;
    }
    __syncthreads();
    int nlo = bnds[0], nhi = bnds[1];
    int e0 = starts[nlo], e1 = starts[nhi];
    _Float16* row = SG + (size_t)g * K2;

    if (kg < 8) {
        float acc[4] = {};
        for (int base = e0; base < e1; base += CHUNK) {
            int ne = min(CHUNK, e1 - base);
            if (t < ne) { int e = elist[base + t]; el[t] = e; sl[t] = src[e]; }
            __syncthreads();
            int ie = 0;
            for (; ie + 8 <= ne; ie += 8) {
                float hv[8]; float4 ev[8];
#pragma unroll
                for (int u = 0; u < 8; ++u) hv[u] = (float)h[(size_t)sl[ie + u] * 256 + t];
#pragma unroll
                for (int u = 0; u < 8; ++u) ev[u] = *(const float4*)&ea[(size_t)el[ie + u] * 32 + kg * 4];
#pragma unroll
                for (int u = 0; u < 8; ++u) {
                    acc[0] += ev[u].x * hv[u]; acc[1] += ev[u].y * hv[u];
                    acc[2] += ev[u].z * hv[u]; acc[3] += ev[u].w * hv[u];
                }
            }
            for (; ie < ne; ++ie) {
                float hv = (float)h[(size_t)sl[ie] * 256 + t];
                float4 ev = *(const float4*)&ea[(size_t)el[ie] * 32 + kg * 4];
                acc[0] += ev.x * hv; acc[1] += ev.y * hv;
                acc[2] += ev.z * hv; acc[3] += ev.w * hv;
            }
            __syncthreads();
        }
#pragma unroll
        for (int j = 0; j < 4; ++j)
            row[(kg * 4 + j) * 256 + t] = (_Float16)acc[j];
    } else {
        float a32 = 0.f;
        for (int base = e0; base < e1; base += CHUNK) {
            int ne = min(CHUNK, e1 - base);
            if (t < ne) sl[t] = src[elist[base + t]];
            __syncthreads();
            int ie = 0;
            for (; ie + 8 <= ne; ie += 8) {
                float hv[8];
#pragma unroll
                for (int u = 0; u < 8; ++u) hv[u] = (float)h[(size_t)sl[ie + u] * 256 + t];
#pragma unroll
                for (int u = 0; u < 8; ++u) a32 += hv[u];
            }
            for (; ie < ne; ++ie)
                a32 += (float)h[(size_t)sl[ie] * 256 + t];
            __syncthreads();
        }
        float aug = 0.f;
        int n = nlo;
        for (; n + 4 <= nhi; n += 4) {
            float hv[4];
#pragma unroll
            for (int u = 0; u < 4; ++u) hv[u] = (float)h[(size_t)(n + u) * 256 + t];
#pragma unroll
            for (int u = 0; u < 4; ++u) aug += hv[u];
        }
        for (; n < nhi; ++n) aug += (float)h[(size_t)n * 256 + t];
        row[32 * 256 + t] = (_Float16)a32;
        row[8448 + t] = (_Float16)aug;
    }
}

// ---------------- pooled conv2 mini-GEMM: [256xK2] @ BT2^T, split-K, f32 partials ----------------
__global__ __launch_bounds__(256, 3) void gemm_sg(const _Float16* __restrict__ A,
                                                  const _Float16* __restrict__ BT,
                                                  float* __restrict__ Cp,
                                                  int K, int NC, int Z) {
    __shared__ _Float16 lds[16384];     // As 128x64 + Bs 128x64
    _Float16* As = lds;
    _Float16* Bs = lds + 128 * 64;
    int tid = threadIdx.x;
    int w = tid >> 6, l = tid & 63;
    int mt = blockIdx.y, nt = blockIdx.x, z = blockIdx.z;
    int c0 = z * NC / Z, c1 = (z + 1) * NC / Z;
    int k0 = c0 * 64;
    int wm = w & 1, wn = w >> 1;

    int lr = l >> 3, lc = l & 7;
    int gc = lc ^ lr;
    const _Float16* gA0 = A  + (size_t)(mt * 128 + w * 32 + lr) * K + k0 + gc * 8;
    const _Float16* gB0 = BT + (size_t)(nt * 128 + w * 32 + lr) * K + k0 + gc * 8;

    int lm = l & 15, q4 = l >> 4;
    int sw = lm & 7;

    floatx4 acc[4][4] = {};

    for (int s = c0; s < c1; ++s) {
#pragma unroll
        for (int q = 0; q < 4; ++q) {
            async_copy16(gA0 + (size_t)q * 8 * K, As + (w * 32 + q * 8) * 64);
            async_copy16(gB0 + (size_t)q * 8 * K, Bs + (w * 32 + q * 8) * 64);
        }
        gA0 += 64; gB0 += 64;
        __syncthreads();
#pragma unroll
        for (int kw = 0; kw < 2; ++kw) {
            int ck = ((kw * 4 + q4) ^ sw) * 8;
            half8v af[4], bf[4];
#pragma unroll
            for (int i = 0; i < 4; ++i)
                af[i] = *(const half8v*)&As[(wm * 64 + i * 16 + lm) * 64 + ck];
#pragma unroll
            for (int j = 0; j < 4; ++j)
                bf[j] = *(const half8v*)&Bs[(wn * 64 + j * 16 + lm) * 64 + ck];
#pragma unroll
            for (int i = 0; i < 4; ++i)
#pragma unroll
                for (int j = 0; j < 4; ++j)
                    acc[i][j] = __builtin_amdgcn_mfma_f32_16x16x32_f16(af[i], bf[j], acc[i][j], 0, 0, 0);
        }
        __syncthreads();
    }

    float* C = Cp + (size_t)z * (N_GRAPHS * HH);
    int gm0 = mt * 128 + wm * 64, gn0 = nt * 128 + wn * 64;
#pragma unroll
    for (int i = 0; i < 4; ++i)
#pragma unroll
        for (int j = 0; j < 4; ++j)
#pragma unroll
            for (int r = 0; r < 4; ++r)
                C[(size_t)(gm0 + i * 16 + q4 * 4 + r) * HH + gn0 + j * 16 + lm] = acc[i][j][r];
}

// ---------------- readout: reduce partials -> mean + bias2 -> MLP -> sigmoid ----------------
__global__ __launch_bounds__(256) void readout_k(const float* __restrict__ CpS,
                                                 const int* __restrict__ batch,
                                                 const float* __restrict__ bias2,
                                                 const float* __restrict__ l1w,
                                                 const float* __restrict__ l1b,
                                                 const float* __restrict__ l2w,
                                                 const float* __restrict__ l2b,
                                                 float* __restrict__ out) {
    int g = blockIdx.x, t = threadIdx.x;
    __shared__ int bnds[2];
    __shared__ float sp[256];
    __shared__ float sz[128];
    if (t < 2) {
        int target = g + t;
        int lo = 0, hi = N_NODES;
        while (lo < hi) { int mid = (lo + hi) >> 1; if (batch[mid] < target) lo = mid + 1; else hi = mid; }
        bnds[t] = lo;
    }
    __syncthreads();
    int lo = bnds[0], hi = bnds[1];
    float s = 0.f;
#pragma unroll
    for (int zz = 0; zz < NSL3; ++zz)
        s += CpS[(size_t)zz * (N_GRAPHS * HH) + g * 256 + t];
    sp[t] = (hi > lo) ? (s / (float)(hi - lo) + bias2[t]) : 0.f;
    __syncthreads();
    if (t < 128) {
        float a = l1b[t];
#pragma unroll 8
        for (int i = 0; i < 256; ++i) a += sp[i] * l1w[i * 128 + t];
        sz[t] = fmaxf(a, 0.f) * l2w[t];
    }
    __syncthreads();
    for (int ss = 64; ss > 0; ss >>= 1) {
        if (t < ss) sz[t] += sz[t + ss];
        __syncthreads();
    }
    if (t == 0) {
        float zz = sz[0] + l2b[0];
        out[g] = 1.0f / (1.0f + expf(-zz));
    }
}

extern "C" void kernel_launch(void* const* d_in, const int* in_sizes, int n_in,
                              void* d_out, int out_size, void* d_ws, size_t ws_size,
                              hipStream_t stream) {
    const float* x       = (const float*)d_in[0];
    const int*   ei      = (const int*)d_in[1];
    const float* ea      = (const float*)d_in[2];
    const int*   batch   = (const int*)d_in[3];
    const float* nn1_w   = (const float*)d_in[4];
    const float* nn1_b   = (const float*)d_in[5];
    const float* root1_w = (const float*)d_in[6];
    const float* bias1   = (const float*)d_in[7];
    const float* nn2_w   = (const float*)d_in[8];
    const float* nn2_b   = (const float*)d_in[9];
    const float* root2_w = (const float*)d_in[10];
    const float* bias2   = (const float*)d_in[11];
    const float* lin1_w  = (const float*)d_in[12];
    const float* lin1_b  = (const float*)d_in[13];
    const float* lin2_w  = (const float*)d_in[14];
    const float* lin2_b  = (const float*)d_in[15];
    float* out = (float*)d_out;
    float* ws  = (float*)d_ws;

    _Float16* S   = (_Float16*)(ws + OFF_S);    // S1, then SG (time-disjoint)
    _Float16* BT1 = (_Float16*)(ws + OFF_BT1);
    _Float16* BT2 = (_Float16*)(ws + OFF_BT2);
    _Float16* Cp  = (_Float16*)(ws + OFF_CP);   // conv1 fp16 partials
    float*    CpS = ws + OFF_CP;                // then f32 partials for mini-GEMM (time-disjoint)
    _Float16* h   = (_Float16*)(ws + OFF_H);
    int* ip     = (int*)(ws + OFF_INT);
    int* starts = ip;            // 4097
    int* elist  = ip + 4100;     // 8192

    const int* srcv = ei;
    const int* dstv = ei + N_EDGES;

    // 1) CSR + weight pack
    prep_k<<<dim3(1 + NC1 + NC2, 4), 256, 0, stream>>>(
        dstv, starts, elist, nn1_w, nn1_b, root1_w, nn2_w, nn2_b, root2_w, BT1, BT2);

    // 2) conv1 staging: S1 [4096 x 2176] fp16
    s1_k<<<4096, 64, 0, stream>>>(x, ea, srcv, starts, elist, S);

    // 3) conv1 GEMM, split-K=8, fp16 partials
    gemm_f16<<<dim3(2, 32, NSL1), 256, 0, stream>>>(S, BT1, Cp, K1, NC1, NSL1);

    // 4) reduce + bias1 + relu -> h fp16
    hep_k<<<512, 256, 0, stream>>>(Cp, bias1, h);

    // 5) graph-pooled conv2 staging: SG [256 x 8704] fp16, (graph x kgroup) grid, MLP=8
    sg_k<<<dim3(N_GRAPHS, 9), 256, 0, stream>>>(h, ea, srcv, starts, elist, batch, S);

    // 6) pooled conv2 mini-GEMM: [256 x 8704] @ W2aug -> f32 partials, split-K=32
    gemm_sg<<<dim3(2, 2, NSL3), 256, 0, stream>>>(S, BT2, CpS, K2, NC2, NSL3);

    // 7) reduce partials + mean + bias2 + MLP + sigmoid
    readout_k<<<N_GRAPHS, 256, 0, stream>>>(CpS, batch, bias2,
                                            lin1_w, lin1_b, lin2_w, lin2_b, out);
}

// Round 7
// 166.448 us; speedup vs baseline: 1.7024x; 1.0428x over previous
//
#include <hip/hip_runtime.h>
#include <math.h>

#define N_NODES 4096
#define N_EDGES 8192
#define N_GRAPHS 256
#define D_NODE 64
#define D_EDGE 32
#define HH 256

#define K1 2176   // 33*64 (edge-MLP + nn_b rows) + 64 (x augment for root1)
#define K2 8704   // 33*256 + 256 (h augment for root2)
#define NC1 34
#define NC2 136
#define NSL1 8    // split-K slices conv1
#define NSL3 32   // split-K slices pooled conv2 mini-GEMM
#define CHUNK 64  // sg_k edge chunk (LDS-staged ids + ea)

typedef _Float16 half8v __attribute__((ext_vector_type(8)));
typedef _Float16 half4v __attribute__((ext_vector_type(4)));
typedef float floatx4 __attribute__((ext_vector_type(4)));

// ---------------- workspace layout (float offsets) ----------------
static const size_t OFF_S    = 0;              // S1 fp16 [4096x2176]; later SG fp16 [256x8704] (time-disjoint)
static const size_t OFF_BT1  = 17825792;       // BT1 fp16: 256 x 2176 halves
static const size_t OFF_BT2  = 18104320;       // BT2 fp16: 256 x 8704 halves
static const size_t OFF_CP   = 19218432;       // Cpart fp16 (conv1, 8 slices)
static const size_t OFF_H    = 25509888;       // h fp16: 524,288 floats
static const size_t OFF_INT  = 26034176;       // starts[4097]+pad + elist[8192] + gstarts[257]
static const size_t OFF_POOL = 26050560;       // pool f32: 256 x 256

// ---------------- prep: CSR (bx0/by0) + graph bounds (bx0/by1) + weight pack ----------------
__device__ void csr_body(const int* __restrict__ dst,
                         int* __restrict__ starts,
                         int* __restrict__ elist) {
    __shared__ int cnt[4096];
    __shared__ int ps[256];
    int t = threadIdx.x;
#pragma unroll
    for (int i = 0; i < 16; ++i) cnt[t * 16 + i] = 0;
    __syncthreads();
#pragma unroll
    for (int i = 0; i < 32; ++i) atomicAdd(&cnt[dst[i * 256 + t]], 1);
    __syncthreads();
    int v[16]; int s = 0;
#pragma unroll
    for (int i = 0; i < 16; ++i) { v[i] = cnt[t * 16 + i]; s += v[i]; }
    ps[t] = s;
    __syncthreads();
    for (int off = 1; off < 256; off <<= 1) {
        int tv = (t >= off) ? ps[t - off] : 0;
        __syncthreads();
        ps[t] += tv;
        __syncthreads();
    }
    int excl = ps[t] - s;
#pragma unroll
    for (int i = 0; i < 16; ++i) {
        starts[t * 16 + i] = excl;
        cnt[t * 16 + i] = excl;       // becomes cursor
        excl += v[i];
    }
    if (t == 255) starts[4096] = excl;
    __syncthreads();
#pragma unroll
    for (int i = 0; i < 32; ++i) {
        int e = i * 256 + t;
        int d = dst[e];
        int p = atomicAdd(&cnt[d], 1);
        elist[p] = e;
    }
}

// graph->node lower bounds, once for the whole pipeline (removes per-block bsearch)
__device__ void gstarts_body(const int* __restrict__ batch, int* __restrict__ gstarts) {
    int t = threadIdx.x;
    int lo = 0, hi = N_NODES;
    while (lo < hi) { int mid = (lo + hi) >> 1; if (batch[mid] < t) lo = mid + 1; else hi = mid; }
    gstarts[t] = lo;
    if (t == 0) gstarts[N_GRAPHS] = N_NODES;
}

__device__ void packT_body(const float* __restrict__ w,
                           const float* __restrict__ b,
                           const float* __restrict__ rw,
                           _Float16* __restrict__ BT,
                           int kk0, int o0, int K,
                           int wlim, int blim, int wshift, int wmask, int wrow) {
    __shared__ float T[64][65];
    int t = threadIdx.x;
    int ol = t & 63, kb = t >> 6;
#pragma unroll
    for (int p = 0; p < 16; ++p) {
        int kl = p * 4 + kb;
        int kk = kk0 + kl, o = o0 + ol;
        float v;
        if (kk < wlim)      v = w[(kk >> wshift) * wrow + (kk & wmask) * 256 + o];
        else if (kk < blim) v = b[(kk - wlim) * 256 + o];
        else                v = rw[(kk - blim) * 256 + o];
        T[kl][ol] = v;
    }
    __syncthreads();
    int kl2 = t & 63, ob = t >> 6;
#pragma unroll
    for (int p = 0; p < 16; ++p) {
        int ol2 = p * 4 + ob;
        BT[(size_t)(o0 + ol2) * K + kk0 + kl2] = (_Float16)T[kl2][ol2];
    }
}

__global__ __launch_bounds__(256) void prep_k(const int* __restrict__ dst,
                                              const int* __restrict__ batch,
                                              int* __restrict__ starts,
                                              int* __restrict__ elist,
                                              int* __restrict__ gstarts,
                                              const float* __restrict__ w1,
                                              const float* __restrict__ b1,
                                              const float* __restrict__ r1,
                                              const float* __restrict__ w2,
                                              const float* __restrict__ b2,
                                              const float* __restrict__ r2,
                                              _Float16* __restrict__ BT1,
                                              _Float16* __restrict__ BT2) {
    int bx = blockIdx.x, by = blockIdx.y;
    if (bx == 0) {
        if (by == 0) csr_body(dst, starts, elist);
        else if (by == 1) gstarts_body(batch, gstarts);
        return;
    }
    int pbx = bx - 1, o0 = by * 64;
    if (pbx < NC1)
        packT_body(w1, b1, r1, BT1, pbx * 64, o0, K1, 2048, 2112, 6, 63, 16384);
    else
        packT_body(w2, b2, r2, BT2, (pbx - NC1) * 64, o0, K2, 8192, 8448, 8, 255, 65536);
}

// ---------------- conv1 staging: 4 nodes per block (64-lane group each) ----------------
__global__ __launch_bounds__(256) void s1_k(const float* __restrict__ x,
                                            const float* __restrict__ ea,
                                            const int* __restrict__ src,
                                            const int* __restrict__ starts,
                                            const int* __restrict__ elist,
                                            _Float16* __restrict__ S) {
    int t = threadIdx.x;
    int n = blockIdx.x * 4 + (t >> 6);
    int tl = t & 63;
    int cg = tl & 7, kg = tl >> 3;
    int i0 = cg * 8;
    float acc[5][8] = {};
    int e0 = starts[n], e1 = starts[n + 1];
    for (int ie = e0; ie < e1; ++ie) {
        int e = elist[ie];
        int sn = src[e];
        float4 f0 = *(const float4*)&x[sn * 64 + i0];
        float4 f1 = *(const float4*)&x[sn * 64 + i0 + 4];
        float xv[8] = {f0.x, f0.y, f0.z, f0.w, f1.x, f1.y, f1.z, f1.w};
#pragma unroll
        for (int j = 0; j < 4; ++j) {
            float va = ea[e * 32 + kg + 8 * j];
#pragma unroll
            for (int c = 0; c < 8; ++c) acc[j][c] += va * xv[c];
        }
        if (kg == 0) {
#pragma unroll
            for (int c = 0; c < 8; ++c) acc[4][c] += xv[c];   // k=32, ea'=1
        }
    }
    _Float16* row = S + (size_t)n * K1;
#pragma unroll
    for (int j = 0; j < 4; ++j) {
        int k = kg + 8 * j;
        half8v o;
#pragma unroll
        for (int c = 0; c < 8; ++c) o[c] = (_Float16)acc[j][c];
        *(half8v*)&row[k * 64 + i0] = o;
    }
    if (kg == 0) {
        half8v o;
#pragma unroll
        for (int c = 0; c < 8; ++c) o[c] = (_Float16)acc[4][c];
        *(half8v*)&row[32 * 64 + i0] = o;
    }
    if (kg == 1) {
        float4 f0 = *(const float4*)&x[n * 64 + i0];
        float4 f1 = *(const float4*)&x[n * 64 + i0 + 4];
        half8v o;
        o[0] = (_Float16)f0.x; o[1] = (_Float16)f0.y; o[2] = (_Float16)f0.z; o[3] = (_Float16)f0.w;
        o[4] = (_Float16)f1.x; o[5] = (_Float16)f1.y; o[6] = (_Float16)f1.z; o[7] = (_Float16)f1.w;
        *(half8v*)&row[2112 + i0] = o;
    }
}

// ---------------- async global->LDS helper ----------------
__device__ __forceinline__ void async_copy16(const void* g, void* l) {
    __builtin_amdgcn_global_load_lds(
        (__attribute__((address_space(1))) unsigned int*)(g),
        (__attribute__((address_space(3))) unsigned int*)(l), 16, 0, 0);
}

// ---------------- conv1 GEMM: 4-wave 128x128, fp16 partials (proven r7 path) ----------------
__global__ __launch_bounds__(256, 3) void gemm_f16(const _Float16* __restrict__ A,
                                                   const _Float16* __restrict__ BT,
                                                   _Float16* __restrict__ Cpart,
                                                   int K, int NC, int Z) {
    __shared__ _Float16 lds[17408];     // 34 KB: staging 2x(128x64); epilogue 4x(64x68)
    _Float16* As = lds;
    _Float16* Bs = lds + 128 * 64;
    int tid = threadIdx.x;
    int w = tid >> 6, l = tid & 63;
    int mt = blockIdx.y, nt = blockIdx.x, z = blockIdx.z;
    int c0 = z * NC / Z, c1 = (z + 1) * NC / Z;
    int k0 = c0 * 64;
    int wm = w & 1, wn = w >> 1;

    int lr = l >> 3, lc = l & 7;
    int gc = lc ^ lr;
    const _Float16* gA0 = A  + (size_t)(mt * 128 + w * 32 + lr) * K + k0 + gc * 8;
    const _Float16* gB0 = BT + (size_t)(nt * 128 + w * 32 + lr) * K + k0 + gc * 8;

    int lm = l & 15, q4 = l >> 4;
    int sw = lm & 7;

    floatx4 acc[4][4] = {};

    for (int s = c0; s < c1; ++s) {
#pragma unroll
        for (int q = 0; q < 4; ++q) {
            async_copy16(gA0 + (size_t)q * 8 * K, As + (w * 32 + q * 8) * 64);
            async_copy16(gB0 + (size_t)q * 8 * K, Bs + (w * 32 + q * 8) * 64);
        }
        gA0 += 64; gB0 += 64;
        __syncthreads();
#pragma unroll
        for (int kw = 0; kw < 2; ++kw) {
            int ck = ((kw * 4 + q4) ^ sw) * 8;
            half8v af[4], bf[4];
#pragma unroll
            for (int i = 0; i < 4; ++i)
                af[i] = *(const half8v*)&As[(wm * 64 + i * 16 + lm) * 64 + ck];
#pragma unroll
            for (int j = 0; j < 4; ++j)
                bf[j] = *(const half8v*)&Bs[(wn * 64 + j * 16 + lm) * 64 + ck];
#pragma unroll
            for (int i = 0; i < 4; ++i)
#pragma unroll
                for (int j = 0; j < 4; ++j)
                    acc[i][j] = __builtin_amdgcn_mfma_f32_16x16x32_f16(af[i], bf[j], acc[i][j], 0, 0, 0);
        }
        __syncthreads();
    }

    // coalesced epilogue via LDS
    _Float16* ep = lds + w * 4352;      // 64*68 halves
#pragma unroll
    for (int i = 0; i < 4; ++i)
#pragma unroll
        for (int j = 0; j < 4; ++j)
#pragma unroll
            for (int r = 0; r < 4; ++r)
                ep[(i * 16 + q4 * 4 + r) * 68 + j * 16 + lm] = (_Float16)acc[i][j][r];
    __syncthreads();
    _Float16* Cp = Cpart + (size_t)z * (N_NODES * HH);
    int row8 = l >> 3, colg = (l & 7) * 8;
    int gm0 = mt * 128 + wm * 64, gn0 = nt * 128 + wn * 64;
#pragma unroll
    for (int i8 = 0; i8 < 8; ++i8) {
        int rr = i8 * 8 + row8;
        half4v lo = *(const half4v*)&ep[rr * 68 + colg];
        half4v hi = *(const half4v*)&ep[rr * 68 + colg + 4];
        half8v v;
        v[0] = lo[0]; v[1] = lo[1]; v[2] = lo[2]; v[3] = lo[3];
        v[4] = hi[0]; v[5] = hi[1]; v[6] = hi[2]; v[7] = hi[3];
        *(half8v*)&Cp[(size_t)(gm0 + rr) * HH + gn0 + colg] = v;
    }
}

// ---------------- conv1 epilogue: split-K reduce + bias1 + relu -> h fp16 (+ zero pool) ----------------
__global__ __launch_bounds__(256) void hep_k(const _Float16* __restrict__ Cp,
                                             const float* __restrict__ bias,
                                             _Float16* __restrict__ h,
                                             float* __restrict__ pool) {
    if (blockIdx.x < 256) pool[blockIdx.x * 256 + threadIdx.x] = 0.f;
    int idx = (blockIdx.x * 256 + threadIdx.x) * 8;
    float a[8] = {};
#pragma unroll
    for (int zz = 0; zz < NSL1; ++zz) {
        half8v v = *(const half8v*)(Cp + (size_t)zz * (N_NODES * HH) + idx);
#pragma unroll
        for (int j = 0; j < 8; ++j) a[j] += (float)v[j];
    }
    int col = idx & 255;
    half8v o;
#pragma unroll
    for (int j = 0; j < 8; ++j) o[j] = (_Float16)fmaxf(a[j] + bias[col + j], 0.f);
    *(half8v*)(h + idx) = o;
}

// ---------------- SG staging: graph-pooled lifted matrix, (graph x k-half) grid ----------------
// SG[g, k*256+i] = sum_{e: dst in g} ea'[e,k] * h[src[e], i]   (ea'[.,32] = 1)
// SG[g, 8448+i]  = sum_{n in g} h[n,i]                          (root2 augment)
// Grid (256, 2): ks=0 -> k 0..15; ks=1 -> k 16..31 + k=32 + augment.
// One stage of elist/src/ea per block (was 9x in the kgroup version); thread t
// owns column t with acc[16] registers; edges unrolled by 4.
// Accumulation order over ie ascending per (k,col) -> identical numerics to r6.
__global__ __launch_bounds__(256) void sg_k(const _Float16* __restrict__ h,
                                            const float* __restrict__ ea,
                                            const int* __restrict__ src,
                                            const int* __restrict__ starts,
                                            const int* __restrict__ elist,
                                            const int* __restrict__ gstarts,
                                            _Float16* __restrict__ SG) {
    int g = blockIdx.x, ks = blockIdx.y, t = threadIdx.x;
    __shared__ int sl[CHUNK];
    __shared__ int el[CHUNK];
    __shared__ float eaS[CHUNK * 32];   // 8 KB
    int nlo = gstarts[g], nhi = gstarts[g + 1];
    int e0 = starts[nlo], e1 = starts[nhi];
    _Float16* row = SG + (size_t)g * K2;
    int kbase = ks * 16;

    float acc[16] = {};
    float a32 = 0.f;
    for (int base = e0; base < e1; base += CHUNK) {
        int ne = min(CHUNK, e1 - base);
        if (t < ne) { int e = elist[base + t]; el[t] = e; sl[t] = src[e]; }
        __syncthreads();
        for (int j = t; j < ne * 32; j += 256)
            eaS[j] = ea[(size_t)el[j >> 5] * 32 + (j & 31)];
        __syncthreads();
        int ie = 0;
        for (; ie + 4 <= ne; ie += 4) {
            float hv[4];
#pragma unroll
            for (int u = 0; u < 4; ++u) hv[u] = (float)h[(size_t)sl[ie + u] * 256 + t];
#pragma unroll
            for (int u = 0; u < 4; ++u) {
                const float* er = &eaS[(ie + u) * 32 + kbase];
#pragma unroll
                for (int q = 0; q < 4; ++q) {
                    float4 ev = *(const float4*)&er[q * 4];
                    acc[q * 4 + 0] += ev.x * hv[u]; acc[q * 4 + 1] += ev.y * hv[u];
                    acc[q * 4 + 2] += ev.z * hv[u]; acc[q * 4 + 3] += ev.w * hv[u];
                }
                if (ks == 1) a32 += hv[u];
            }
        }
        for (; ie < ne; ++ie) {
            float hv = (float)h[(size_t)sl[ie] * 256 + t];
            const float* er = &eaS[ie * 32 + kbase];
#pragma unroll
            for (int q = 0; q < 4; ++q) {
                float4 ev = *(const float4*)&er[q * 4];
                acc[q * 4 + 0] += ev.x * hv; acc[q * 4 + 1] += ev.y * hv;
                acc[q * 4 + 2] += ev.z * hv; acc[q * 4 + 3] += ev.w * hv;
            }
            if (ks == 1) a32 += hv;
        }
        __syncthreads();
    }
#pragma unroll
    for (int j = 0; j < 16; ++j)
        row[(kbase + j) * 256 + t] = (_Float16)acc[j];
    if (ks == 1) {
        float aug = 0.f;
        int n = nlo;
        for (; n + 4 <= nhi; n += 4) {
            float hv[4];
#pragma unroll
            for (int u = 0; u < 4; ++u) hv[u] = (float)h[(size_t)(n + u) * 256 + t];
#pragma unroll
            for (int u = 0; u < 4; ++u) aug += hv[u];
        }
        for (; n < nhi; ++n) aug += (float)h[(size_t)n * 256 + t];
        row[32 * 256 + t] = (_Float16)a32;
        row[8448 + t] = (_Float16)aug;
    }
}

// ---------------- pooled conv2 mini-GEMM: [256xK2] @ BT2^T, split-K, pool atomics ----------------
__global__ __launch_bounds__(256, 3) void gemm_sg(const _Float16* __restrict__ A,
                                                  const _Float16* __restrict__ BT,
                                                  float* __restrict__ pool,
                                                  int K, int NC, int Z) {
    __shared__ _Float16 lds[16384];     // As 128x64 + Bs 128x64
    _Float16* As = lds;
    _Float16* Bs = lds + 128 * 64;
    int tid = threadIdx.x;
    int w = tid >> 6, l = tid & 63;
    int mt = blockIdx.y, nt = blockIdx.x, z = blockIdx.z;
    int c0 = z * NC / Z, c1 = (z + 1) * NC / Z;
    int k0 = c0 * 64;
    int wm = w & 1, wn = w >> 1;

    int lr = l >> 3, lc = l & 7;
    int gc = lc ^ lr;
    const _Float16* gA0 = A  + (size_t)(mt * 128 + w * 32 + lr) * K + k0 + gc * 8;
    const _Float16* gB0 = BT + (size_t)(nt * 128 + w * 32 + lr) * K + k0 + gc * 8;

    int lm = l & 15, q4 = l >> 4;
    int sw = lm & 7;

    floatx4 acc[4][4] = {};

    for (int s = c0; s < c1; ++s) {
#pragma unroll
        for (int q = 0; q < 4; ++q) {
            async_copy16(gA0 + (size_t)q * 8 * K, As + (w * 32 + q * 8) * 64);
            async_copy16(gB0 + (size_t)q * 8 * K, Bs + (w * 32 + q * 8) * 64);
        }
        gA0 += 64; gB0 += 64;
        __syncthreads();
#pragma unroll
        for (int kw = 0; kw < 2; ++kw) {
            int ck = ((kw * 4 + q4) ^ sw) * 8;
            half8v af[4], bf[4];
#pragma unroll
            for (int i = 0; i < 4; ++i)
                af[i] = *(const half8v*)&As[(wm * 64 + i * 16 + lm) * 64 + ck];
#pragma unroll
            for (int j = 0; j < 4; ++j)
                bf[j] = *(const half8v*)&Bs[(wn * 64 + j * 16 + lm) * 64 + ck];
#pragma unroll
            for (int i = 0; i < 4; ++i)
#pragma unroll
                for (int j = 0; j < 4; ++j)
                    acc[i][j] = __builtin_amdgcn_mfma_f32_16x16x32_f16(af[i], bf[j], acc[i][j], 0, 0, 0);
        }
        __syncthreads();
    }

    // rows of this GEMM are graphs: atomically fold split-K slices into pool
    int gm0 = mt * 128 + wm * 64, gn0 = nt * 128 + wn * 64;
#pragma unroll
    for (int i = 0; i < 4; ++i)
#pragma unroll
        for (int j = 0; j < 4; ++j)
#pragma unroll
            for (int r = 0; r < 4; ++r)
                atomicAdd(&pool[(size_t)(gm0 + i * 16 + q4 * 4 + r) * HH + gn0 + j * 16 + lm],
                          acc[i][j][r]);
}

// ---------------- readout: pool -> mean + bias2 -> MLP -> sigmoid ----------------
__global__ __launch_bounds__(256) void readout_k(const float* __restrict__ pool,
                                                 const int* __restrict__ gstarts,
                                                 const float* __restrict__ bias2,
                                                 const float* __restrict__ l1w,
                                                 const float* __restrict__ l1b,
                                                 const float* __restrict__ l2w,
                                                 const float* __restrict__ l2b,
                                                 float* __restrict__ out) {
    int g = blockIdx.x, t = threadIdx.x;
    __shared__ float sp[256];
    __shared__ float sz[128];
    int lo = gstarts[g], hi = gstarts[g + 1];
    sp[t] = (hi > lo) ? (pool[g * 256 + t] / (float)(hi - lo) + bias2[t]) : 0.f;
    __syncthreads();
    if (t < 128) {
        float a = l1b[t];
#pragma unroll 8
        for (int i = 0; i < 256; ++i) a += sp[i] * l1w[i * 128 + t];
        sz[t] = fmaxf(a, 0.f) * l2w[t];
    }
    __syncthreads();
    for (int ss = 64; ss > 0; ss >>= 1) {
        if (t < ss) sz[t] += sz[t + ss];
        __syncthreads();
    }
    if (t == 0) {
        float zz = sz[0] + l2b[0];
        out[g] = 1.0f / (1.0f + expf(-zz));
    }
}

extern "C" void kernel_launch(void* const* d_in, const int* in_sizes, int n_in,
                              void* d_out, int out_size, void* d_ws, size_t ws_size,
                              hipStream_t stream) {
    const float* x       = (const float*)d_in[0];
    const int*   ei      = (const int*)d_in[1];
    const float* ea      = (const float*)d_in[2];
    const int*   batch   = (const int*)d_in[3];
    const float* nn1_w   = (const float*)d_in[4];
    const float* nn1_b   = (const float*)d_in[5];
    const float* root1_w = (const float*)d_in[6];
    const float* bias1   = (const float*)d_in[7];
    const float* nn2_w   = (const float*)d_in[8];
    const float* nn2_b   = (const float*)d_in[9];
    const float* root2_w = (const float*)d_in[10];
    const float* bias2   = (const float*)d_in[11];
    const float* lin1_w  = (const float*)d_in[12];
    const float* lin1_b  = (const float*)d_in[13];
    const float* lin2_w  = (const float*)d_in[14];
    const float* lin2_b  = (const float*)d_in[15];
    float* out = (float*)d_out;
    float* ws  = (float*)d_ws;

    _Float16* S   = (_Float16*)(ws + OFF_S);    // S1, then SG (time-disjoint)
    _Float16* BT1 = (_Float16*)(ws + OFF_BT1);
    _Float16* BT2 = (_Float16*)(ws + OFF_BT2);
    _Float16* Cp  = (_Float16*)(ws + OFF_CP);   // conv1 fp16 partials
    _Float16* h   = (_Float16*)(ws + OFF_H);
    int* ip      = (int*)(ws + OFF_INT);
    int* starts  = ip;             // 4097 (+3 pad)
    int* elist   = ip + 4100;      // 8192
    int* gstarts = ip + 12292;     // 257
    float* pool  = ws + OFF_POOL;  // 256 x 256 f32

    const int* srcv = ei;
    const int* dstv = ei + N_EDGES;

    // 1) CSR + graph bounds + weight pack
    prep_k<<<dim3(1 + NC1 + NC2, 4), 256, 0, stream>>>(
        dstv, batch, starts, elist, gstarts,
        nn1_w, nn1_b, root1_w, nn2_w, nn2_b, root2_w, BT1, BT2);

    // 2) conv1 staging: S1 [4096 x 2176] fp16, 4 nodes/block
    s1_k<<<1024, 256, 0, stream>>>(x, ea, srcv, starts, elist, S);

    // 3) conv1 GEMM, split-K=8, fp16 partials
    gemm_f16<<<dim3(2, 32, NSL1), 256, 0, stream>>>(S, BT1, Cp, K1, NC1, NSL1);

    // 4) reduce + bias1 + relu -> h fp16 (+ zero pool)
    hep_k<<<512, 256, 0, stream>>>(Cp, bias1, h, pool);

    // 5) graph-pooled conv2 staging: SG [256 x 8704] fp16, (graph x k-half) grid
    sg_k<<<dim3(N_GRAPHS, 2), 256, 0, stream>>>(h, ea, srcv, starts, elist, gstarts, S);

    // 6) pooled conv2 mini-GEMM -> pool f32 atomics, split-K=32
    gemm_sg<<<dim3(2, 2, NSL3), 256, 0, stream>>>(S, BT2, pool, K2, NC2, NSL3);

    // 7) mean + bias2 + MLP + sigmoid
    readout_k<<<N_GRAPHS, 256, 0, stream>>>(pool, gstarts, bias2,
                                            lin1_w, lin1_b, lin2_w, lin2_b, out);
}